// Round 12
// baseline (237.138 us; speedup 1.0000x reference)
//
#include <hip/hip_runtime.h>
#include <hip/hip_bf16.h>

// Problem dims: B=16, N=1024, E=d_head=128, H=8; M = 16384 rows
typedef __bf16 bf16x8 __attribute__((ext_vector_type(8)));
typedef _Float16 f16x4 __attribute__((ext_vector_type(4)));
typedef float f32x4 __attribute__((ext_vector_type(4)));

__device__ __forceinline__ unsigned short f2bf(float f) {
  union { __hip_bfloat16 h; unsigned short u; } cv;
  cv.h = __float2bfloat16(f);
  return cv.u;
}
__device__ __forceinline__ unsigned short f2h(float f) {
  union { _Float16 h; unsigned short u; } cv;
  cv.h = (_Float16)f;
  return cv.u;
}

__device__ __forceinline__ bf16x8 ld_frag(const unsigned short* p) {
  bf16x8 v;
  __builtin_memcpy(&v, __builtin_assume_aligned(p, 16), 16);
  return v;
}
__device__ __forceinline__ f16x4 ld_h4(const unsigned short* p) {
  f16x4 v;
  __builtin_memcpy(&v, __builtin_assume_aligned(p, 8), 8);
  return v;
}
__device__ __forceinline__ uint4 ld16(const unsigned short* p) {
  uint4 v;
  __builtin_memcpy(&v, __builtin_assume_aligned(p, 16), 16);
  return v;
}
__device__ __forceinline__ void st16(unsigned short* p, uint4 v) {
  __builtin_memcpy(__builtin_assume_aligned(p, 16), &v, 16);
}
// async global->LDS DMA, 16 B per lane; lds dest is wave-uniform base + lane*16
__device__ __forceinline__ void dma16(const unsigned short* g, unsigned short* l) {
  __builtin_amdgcn_global_load_lds((const __attribute__((address_space(1))) void*)g,
                                   (__attribute__((address_space(3))) void*)l, 16, 0, 0);
}

// ---------------- fused prolog: LayerNorm + both weight transposes ----------
__global__ __launch_bounds__(256) void prolog_kernel(const float* __restrict__ x,
                                                     const float* __restrict__ lw,
                                                     const float* __restrict__ lb,
                                                     const float* __restrict__ w_qkv,
                                                     const float* __restrict__ w_proj,
                                                     unsigned short* __restrict__ xn,
                                                     unsigned short* __restrict__ wqkvT,
                                                     unsigned short* __restrict__ wprojT) {
  __shared__ float tile[32][33];
  int idx = blockIdx.x;
  if (idx < 4096) {
    int wave = threadIdx.x >> 6;
    int lane = threadIdx.x & 63;
    int row = idx * 4 + wave;
    const float* xr = x + (size_t)row * 128;
    float2 v = *reinterpret_cast<const float2*>(xr + lane * 2);
    float s1 = v.x + v.y;
    float s2 = v.x * v.x + v.y * v.y;
#pragma unroll
    for (int off = 32; off > 0; off >>= 1) {
      s1 += __shfl_xor(s1, off, 64);
      s2 += __shfl_xor(s2, off, 64);
    }
    float mu = s1 * (1.0f / 128.0f);
    float var = s2 * (1.0f / 128.0f) - mu * mu;
    float rstd = rsqrtf(var + 1e-5f);
    float a0 = (v.x - mu) * rstd * lw[lane * 2] + lb[lane * 2];
    float a1 = (v.y - mu) * rstd * lw[lane * 2 + 1] + lb[lane * 2 + 1];
    unsigned int pk = (unsigned int)f2bf(a0) | ((unsigned int)f2bf(a1) << 16);
    *reinterpret_cast<unsigned int*>(xn + (size_t)row * 128 + lane * 2) = pk;
    return;
  }
  const float* in;
  unsigned short* out;
  int R, C, cb, rb;
  if (idx < 4480) {
    int rem = idx - 4096;
    in = w_qkv; out = wqkvT; R = 128; C = 3072;
    cb = rem % 96; rb = rem / 96;
  } else {
    int rem = idx - 4480;
    in = w_proj; out = wprojT; R = 1024; C = 128;
    cb = rem % 4; rb = rem / 4;
  }
  int tx = threadIdx.x & 31, ty = threadIdx.x >> 5;
  int c0 = cb * 32, r0 = rb * 32;
#pragma unroll
  for (int k = 0; k < 4; k++)
    tile[ty + 8 * k][tx] = in[(size_t)(r0 + ty + 8 * k) * C + c0 + tx];
  __syncthreads();
#pragma unroll
  for (int k = 0; k < 4; k++)
    out[(size_t)(c0 + ty + 8 * k) * R + r0 + tx] = f2bf(tile[tx][ty + 8 * k]);
}

// ---------------- bias init: out[row][col] = b_proj[col] --------------------
__global__ __launch_bounds__(256) void bias_init(const float* __restrict__ bias,
                                                 float* __restrict__ out) {
  int i = blockIdx.x * 256 + threadIdx.x;  // each thread one float4
  float4 bv = *reinterpret_cast<const float4*>(bias + (i & 31) * 4);
  reinterpret_cast<float4*>(out)[i] = bv;
}

// ---------------- QKV GEMM, 128x128 tile, BK=64 x2 ----------------
// Q cols pre-scaled by scale[h]; Q/K blocks accumulate C^T (operand swap)
// -> epilogue packs ushort4 stores. V cols -> Vt[bh][d][n] fp16.
__global__ __launch_bounds__(256) void qkv_gemm(const unsigned short* __restrict__ A,
                                                const unsigned short* __restrict__ Bt,
                                                const float* __restrict__ scale,
                                                unsigned short* __restrict__ qk,
                                                unsigned short* __restrict__ Vt) {
  __shared__ unsigned short Al[128 * 72];
  __shared__ unsigned short Bl[128 * 72];
  int t = threadIdx.x;
  int i0 = blockIdx.x * 128, c0 = blockIdx.y * 128;
  int lg = t & 7, rr = t >> 3;  // granule 0..7, row 0..31
  int w = t >> 6, lane = t & 63, l15 = lane & 15, quad = lane >> 4;
  int wy = (w >> 1) * 64, wx = (w & 1) * 64;
  const f32x4 fz = {0.f, 0.f, 0.f, 0.f};
  f32x4 acc[4][4];
#pragma unroll
  for (int i = 0; i < 4; i++)
#pragma unroll
    for (int j = 0; j < 4; j++) acc[i][j] = fz;
  bool qkblk = (blockIdx.y < 16);

#pragma unroll
  for (int kt = 0; kt < 2; kt++) {
    int k0 = kt * 64;
    uint4 areg[4], breg[4];
#pragma unroll
    for (int p = 0; p < 4; p++)
      areg[p] = ld16(&A[(size_t)(i0 + rr + 32 * p) * 128 + k0 + lg * 8]);
#pragma unroll
    for (int p = 0; p < 4; p++)
      breg[p] = ld16(&Bt[(size_t)(c0 + rr + 32 * p) * 128 + k0 + lg * 8]);
    __syncthreads();
#pragma unroll
    for (int p = 0; p < 4; p++) st16(&Al[(rr + 32 * p) * 72 + lg * 8], areg[p]);
#pragma unroll
    for (int p = 0; p < 4; p++) st16(&Bl[(rr + 32 * p) * 72 + lg * 8], breg[p]);
    __syncthreads();
#pragma unroll
    for (int ks = 0; ks < 2; ks++) {
      bf16x8 af[4], bfr[4];
#pragma unroll
      for (int i = 0; i < 4; i++)
        af[i] = ld_frag(&Al[(wy + 16 * i + l15) * 72 + 32 * ks + quad * 8]);
#pragma unroll
      for (int j = 0; j < 4; j++)
        bfr[j] = ld_frag(&Bl[(wx + 16 * j + l15) * 72 + 32 * ks + quad * 8]);
      if (qkblk) {  // C^T: l15 = out row, quad*4+r = out col
#pragma unroll
        for (int i = 0; i < 4; i++)
#pragma unroll
          for (int j = 0; j < 4; j++)
            acc[i][j] = __builtin_amdgcn_mfma_f32_16x16x32_bf16(bfr[j], af[i], acc[i][j], 0, 0, 0);
      } else {
#pragma unroll
        for (int i = 0; i < 4; i++)
#pragma unroll
          for (int j = 0; j < 4; j++)
            acc[i][j] = __builtin_amdgcn_mfma_f32_16x16x32_bf16(af[i], bfr[j], acc[i][j], 0, 0, 0);
      }
    }
  }
  if (qkblk) {
    float qsc = (blockIdx.y < 8) ? scale[blockIdx.y] : 1.0f;  // plain scale; attn uses __expf
#pragma unroll
    for (int i = 0; i < 4; i++)
#pragma unroll
      for (int j = 0; j < 4; j++) {
        int row = i0 + wy + 16 * i + l15;
        int col = c0 + wx + 16 * j + quad * 4;
        ushort4 pk;
        pk.x = f2bf(acc[i][j][0] * qsc); pk.y = f2bf(acc[i][j][1] * qsc);
        pk.z = f2bf(acc[i][j][2] * qsc); pk.w = f2bf(acc[i][j][3] * qsc);
        *reinterpret_cast<ushort4*>(qk + (size_t)row * 2048 + col) = pk;
      }
  } else {
    int vc0 = (blockIdx.y - 16) * 128;
#pragma unroll
    for (int i = 0; i < 4; i++)
#pragma unroll
      for (int j = 0; j < 4; j++) {
        int vcol = vc0 + wx + 16 * j + l15;   // 0..1023
        int hh = vcol >> 7, dd = vcol & 127;
        int row0 = i0 + wy + 16 * i + quad * 4;
        int bb = row0 >> 10, nn = row0 & 1023;
        ushort4 pk;
        pk.x = f2h(acc[i][j][0]); pk.y = f2h(acc[i][j][1]);
        pk.z = f2h(acc[i][j][2]); pk.w = f2h(acc[i][j][3]);
        *reinterpret_cast<ushort4*>(Vt + (size_t)(bb * 8 + hh) * 131072 +
                                    (size_t)dd * 1024 + nn) = pk;
      }
  }
}

// ---------------- Flash attention + fused output projection -----------------
// Main loop = R7 config exactly (KV-64 dbuf, lb(256,2), single barrier/kt,
// __expf). Epilogue: normalized O (bf16) -> LDS (stride 136) -> A-frags ->
// 128x128x128 GEMM vs wprojT (global, L2-hot) -> atomicAdd into fp32 out
// (pre-initialized with bias). Removes proj_gemm launch + 96 MB aout traffic.
__global__ __launch_bounds__(256, 2) void attn_kernel(const unsigned short* __restrict__ qk,
                                                      const unsigned short* __restrict__ Vt,
                                                      const unsigned short* __restrict__ wprojT,
                                                      float* __restrict__ out) {
  __shared__ __align__(16) unsigned short smem[32768];  // 64 KB, multi-use
  unsigned short* KlB = smem;          // [2][64*128] = 2 x 16 KB
  unsigned short* VlB = smem + 16384;  // [2][128*64] = 2 x 16 KB
  int t = threadIdx.x;
  int idx = blockIdx.x;
  int bh = idx & 127, qt = idx >> 7;
  int b = bh >> 3, h = bh & 7;
  int q0 = qt * 128;
  int w = t >> 6, lane = t & 63, l15 = lane & 15, quad = lane >> 4;

  // Q fragments (B-operand layout: n=l15=qrow, k=quad*8+j), 2 groups of 16
  bf16x8 qf[2][4];
  {
    const unsigned short* qb = qk + (size_t)(b * 1024) * 2048 + h * 128;
#pragma unroll
    for (int g = 0; g < 2; g++) {
      const unsigned short* qp = qb + (size_t)(q0 + 32 * w + 16 * g + l15) * 2048;
#pragma unroll
      for (int ks = 0; ks < 4; ks++) qf[g][ks] = ld_frag(qp + 32 * ks + quad * 8);
    }
  }
  const f32x4 fz = {0.f, 0.f, 0.f, 0.f};
  f32x4 o[2][8];
#pragma unroll
  for (int g = 0; g < 2; g++)
#pragma unroll
    for (int i = 0; i < 8; i++) o[g][i] = fz;
  float plsum[2] = {0.f, 0.f};

  const unsigned short* kbase = qk + (size_t)(b * 1024) * 2048 + 1024 + h * 128;
  const unsigned short* vbase = Vt + (size_t)bh * 131072;

  // DMA lane mappings (4 K-chunks + 4 V-chunks per wave, 1 KB each; R7 exact)
  int koff[4], voff[4];
#pragma unroll
  for (int i = 0; i < 4; i++) {
    int c = w * 4 + i;                                 // 0..15
    int krow = c * 4 + (lane >> 4);                    // 0..63 (kcol)
    int kg = ((lane & 15) ^ (krow & 7)) * 8;           // 16B granule * 8 shorts
    koff[i] = krow * 2048 + kg;
    int vrow = c * 8 + (lane >> 3);                    // 0..127 (d)
    int vg = ((lane & 7) ^ ((vrow >> 1) & 7)) * 8;
    voff[i] = vrow * 1024 + vg;
  }

  // preload tile 0 into buffer 0
#pragma unroll
  for (int i = 0; i < 4; i++) {
    dma16(kbase + koff[i], &KlB[(w * 4 + i) * 512]);
    dma16(vbase + voff[i], &VlB[(w * 4 + i) * 512]);
  }

  for (int kt = 0; kt < 16; kt++) {
    int k0 = kt * 64;
    __syncthreads();  // drains own tile-kt DMAs (issued ~1 compute phase ago)
    if (kt < 15) {    // prefetch kt+1 into other buffer; drains at next barrier
      int nb = (kt + 1) & 1;
      int kn0 = (kt + 1) * 64;
#pragma unroll
      for (int i = 0; i < 4; i++) {
        dma16(kbase + (size_t)kn0 * 2048 + koff[i], &KlB[nb * 8192 + (w * 4 + i) * 512]);
        dma16(vbase + voff[i] + kn0, &VlB[nb * 8192 + (w * 4 + i) * 512]);
      }
    }
    const unsigned short* Kc = KlB + (kt & 1) * 8192;
    const unsigned short* Vc = VlB + (kt & 1) * 8192;

#pragma unroll
    for (int ct = 0; ct < 4; ct++) {
      // S^T tile: A = K (m=kcol), B = Q (n=qrow); scale pre-folded in Q
      f32x4 acc[2] = {fz, fz};
#pragma unroll
      for (int ks = 0; ks < 4; ks++) {
        bf16x8 kf = ld_frag(&Kc[(16 * ct + l15) * 128 + ((4 * ks + quad) ^ (l15 & 7)) * 8]);
#pragma unroll
        for (int g = 0; g < 2; g++)
          acc[g] = __builtin_amdgcn_mfma_f32_16x16x32_bf16(kf, qf[g][ks], acc[g], 0, 0, 0);
      }
      // __expf + diag-mask (wave-uniform branch) + pack to fp16 A-frags
      f16x4 pa[2];
#pragma unroll
      for (int g = 0; g < 2; g++) {
        if ((q0 + 32 * w + 16 * g) == (k0 + 16 * ct)) {
#pragma unroll
          for (int r = 0; r < 4; r++) {
            float p = ((quad * 4 + r) == l15) ? 0.f : __expf(acc[g][r]);
            plsum[g] += p;
            pa[g][r] = (_Float16)p;
          }
        } else {
#pragma unroll
          for (int r = 0; r < 4; r++) {
            float p = __expf(acc[g][r]);
            plsum[g] += p;
            pa[g][r] = (_Float16)p;
          }
        }
      }
      // O += P_ct * V_ct  (K=16 f16 MFMA; vf: B[k=quad*4+j][n=l15])
#pragma unroll
      for (int c8 = 0; c8 < 8; c8++) {
        f16x4 vf = ld_h4(&Vc[(16 * c8 + l15) * 64 + ((4 * ct + quad) ^ (l15 & 14)) * 4]);
#pragma unroll
        for (int g = 0; g < 2; g++)
          o[g][c8] = __builtin_amdgcn_mfma_f32_16x16x16f16(pa[g], vf, o[g][c8], 0, 0, 0);
      }
    }
  }

  // ---- fused projection epilogue ----
  // row sums: butterfly over quads, redistribute to C-layout rows
  float rl[2][4];
#pragma unroll
  for (int g = 0; g < 2; g++) {
    float s = plsum[g];
    s += __shfl_xor(s, 16, 64);
    s += __shfl_xor(s, 32, 64);
#pragma unroll
    for (int r = 0; r < 4; r++)
      rl[g][r] = 1.0f / __shfl(s, (lane & 48) + quad * 4 + r, 64);
  }
  __syncthreads();  // all PV reads done; also drains stray DMAs -> smem free
  // normalized O (bf16) -> LDS tile [qrow 0..127][d 0..127], stride 136
  unsigned short* Tl = smem;
#pragma unroll
  for (int g = 0; g < 2; g++)
#pragma unroll
    for (int c8 = 0; c8 < 8; c8++)
#pragma unroll
      for (int r = 0; r < 4; r++)
        Tl[(32 * w + 16 * g + quad * 4 + r) * 136 + 16 * c8 + l15] =
            f2bf(o[g][c8][r] * rl[g][r]);
  __syncthreads();

  // out-GEMM: wave w computes qrows 32w..32w+31 vs all 128 out-cols.
  // A from LDS (stride 136, <=2-way), B from global wprojT (L2-hot).
  bf16x8 af[2][4];
#pragma unroll
  for (int gg = 0; gg < 2; gg++)
#pragma unroll
    for (int ks = 0; ks < 4; ks++)
      af[gg][ks] = ld_frag(&Tl[(32 * w + 16 * gg + l15) * 136 + 32 * ks + quad * 8]);
  const unsigned short* wp = wprojT;
  size_t orow0 = (size_t)(b * 1024 + q0 + 32 * w);
#pragma unroll
  for (int jt = 0; jt < 8; jt++) {
    bf16x8 bfr[4];
#pragma unroll
    for (int ks = 0; ks < 4; ks++)
      bfr[ks] = ld_frag(&wp[(size_t)(16 * jt + l15) * 1024 + h * 128 + 32 * ks + quad * 8]);
#pragma unroll
    for (int gg = 0; gg < 2; gg++) {
      f32x4 acc = fz;
#pragma unroll
      for (int ks = 0; ks < 4; ks++)
        acc = __builtin_amdgcn_mfma_f32_16x16x32_bf16(af[gg][ks], bfr[ks], acc, 0, 0, 0);
#pragma unroll
      for (int r = 0; r < 4; r++)
        atomicAdd(&out[(orow0 + 16 * gg + quad * 4 + r) * 128 + 16 * jt + l15], acc[r]);
    }
  }
}

extern "C" void kernel_launch(void* const* d_in, const int* in_sizes, int n_in,
                              void* d_out, int out_size, void* d_ws, size_t ws_size,
                              hipStream_t stream) {
  const float* x      = (const float*)d_in[0];
  const float* ln_w   = (const float*)d_in[1];
  const float* ln_b   = (const float*)d_in[2];
  const float* w_qkv  = (const float*)d_in[3];
  const float* scale  = (const float*)d_in[4];
  const float* w_proj = (const float*)d_in[5];
  const float* b_proj = (const float*)d_in[6];
  float* out = (float*)d_out;

  char* ws = (char*)d_ws;
  unsigned short* xn     = (unsigned short*)(ws);               // 4 MB
  unsigned short* wqkvT  = (unsigned short*)(ws + 4194304);     // 768 KB
  unsigned short* wprojT = (unsigned short*)(ws + 4980736);     // 256 KB
  unsigned short* qk     = (unsigned short*)(ws + 5242880);     // 64 MB [16384][2048] bf16
  unsigned short* Vt     = (unsigned short*)(ws + 72351744);    // 32 MB [128][128][1024] fp16
  // total ws use: ~104 MB (aout eliminated)

  prolog_kernel<<<dim3(4608), dim3(256), 0, stream>>>(x, ln_w, ln_b, w_qkv, w_proj,
                                                      xn, wqkvT, wprojT);
  bias_init<<<dim3(2048), dim3(256), 0, stream>>>(b_proj, out);
  qkv_gemm<<<dim3(128, 24), dim3(256), 0, stream>>>(xn, wqkvT, scale, qk, Vt);
  attn_kernel<<<dim3(1024), dim3(256), 0, stream>>>(qk, Vt, wprojT, out);
}